// Round 5
// baseline (159.245 us; speedup 1.0000x reference)
//
#include <hip/hip_runtime.h>

// PointMassModel: X' = [v, a - g, c*(u - a)], RK4 x 8 substeps, h = DT/8.
// Linear constant-coefficient ODE => whole integration is the affine map
//   s8 = P8 * s + Ku * u + G  (per axis), coefficients host-computed in double.
//
// R5 = R4 (lane-triple, no LDS/barriers) + NONTEMPORAL dwordx3 stores.
// Rationale: R1-R4 (four distinct structures) all tie at ~54 us / 3.26 TB/s
// of through-cache traffic on an L3-resident-dirty working set => backend
// (Infinity-Cache path) bound, not CU-bound. Output is write-once => nt
// store (no-allocate) moves the 75 MB write stream out of L3, freeing its
// bandwidth + capacity for the input streams. Store stays a SINGLE
// global_store_dwordx3 per lane (R2 lesson: split stores -> partial-sector
// RMW write amplification).

#define THREADS 256
#define CHUNK_ENVS 21          // 63 active lanes * 3 floats = 21 envs per wave-chunk
#define CHUNKS_PER_WAVE 4      // consecutive chunks -> contiguous 3 KB region/wave

struct Coeffs {
    float P00, P01, P02;
    float P10, P11, P12;
    float P20, P21, P22;
    float Ku0, Ku1, Ku2;   // u coefficient per row
    float G0,  G1,  G2;    // additive gravity constant per row (z-axis only)
};

struct F3 { float x, y, z; };                               // loads (dwordx3)
typedef float f3v __attribute__((ext_vector_type(3)));      // nt store payload

__global__ __launch_bounds__(THREADS)
void pointmass_kernel(const float* __restrict__ X0,
                      const float* __restrict__ U,
                      float* __restrict__ Out,
                      int envTotal, int chunksTotal, Coeffs cf) {
    const int tid  = blockIdx.x * THREADS + threadIdx.x;
    const int wave = tid >> 6;
    const int lane = tid & 63;
    const int r = lane % 3;        // output row: 0=p, 1=v, 2=a
    const int m = lane / 3;        // triple (env-within-chunk) index; lane 63 inactive

    // loop-invariant per-lane row coefficients
    const float A  = (r == 0) ? cf.P00 : ((r == 1) ? cf.P10 : cf.P20);
    const float B  = (r == 0) ? cf.P01 : ((r == 1) ? cf.P11 : cf.P21);
    const float C  = (r == 0) ? cf.P02 : ((r == 1) ? cf.P12 : cf.P22);
    const float Ku = (r == 0) ? cf.Ku0 : ((r == 1) ? cf.Ku1 : cf.Ku2);
    const float G  = (r == 0) ? cf.G0  : ((r == 1) ? cf.G1  : cf.G2);

    const int chunk0 = wave * CHUNKS_PER_WAVE;

    #pragma unroll
    for (int j = 0; j < CHUNKS_PER_WAVE; ++j) {
        const int chunk = chunk0 + j;
        if (chunk >= chunksTotal) break;
        const int envBase = chunk * CHUNK_ENVS;
        const int remEnvs = envTotal - envBase;                 // >= 1 here
        const int actEnvs = remEnvs < CHUNK_ENVS ? remEnvs : CHUNK_ENVS;
        if (lane < 3 * actEnvs) {
            const size_t xoff = (size_t)envBase * 9 + 9 * m;    // triple base
            const F3 p = *(const F3*)(X0 + xoff);               // shared within triple
            const F3 v = *(const F3*)(X0 + xoff + 3);
            const F3 a = *(const F3*)(X0 + xoff + 6);
            const F3 u = *(const F3*)(U + (size_t)(envBase + m) * 3);

            f3v o;
            o.x = A * p.x + B * v.x + C * a.x + Ku * u.x;
            o.y = A * p.y + B * v.y + C * a.y + Ku * u.y;
            o.z = A * p.z + B * v.z + C * a.z + Ku * u.z + G;   // gravity: z only

            // single-instruction dense nontemporal store: 12 B/lane,
            // wave covers a contiguous 756 B region, no L3 allocation
            __builtin_nontemporal_store(
                o, (f3v*)(Out + (size_t)envBase * 9 + 3 * lane));
        }
    }
}

// ---------------- host-side coefficient computation ----------------
static void mat3_mul(const double A[3][3], const double B[3][3], double C[3][3]) {
    for (int i = 0; i < 3; ++i)
        for (int j = 0; j < 3; ++j) {
            double s = 0.0;
            for (int k = 0; k < 3; ++k) s += A[i][k] * B[k][j];
            C[i][j] = s;
        }
}
static void mat3_copy(const double A[3][3], double B[3][3]) {
    for (int i = 0; i < 3; ++i) for (int j = 0; j < 3; ++j) B[i][j] = A[i][j];
}

extern "C" void kernel_launch(void* const* d_in, const int* in_sizes, int n_in,
                              void* d_out, int out_size, void* d_ws, size_t ws_size,
                              hipStream_t stream) {
    const float* X0 = (const float*)d_in[0];
    const float* U  = (const float*)d_in[1];
    float* Out = (float*)d_out;
    const int envTotal = in_sizes[0] / 9;

    // --- build RK4 closed-form coefficients in double ---
    const double DT = 0.02;
    const double h = DT / 8.0;
    const double c = 0.5 / DT;                 // LMBDA / DT = 25
    double hA[3][3] = {{0, h, 0}, {0, 0, h}, {0, 0, -c * h}};

    double hA2[3][3], hA3[3][3], hA4[3][3];
    mat3_mul(hA, hA, hA2);
    mat3_mul(hA2, hA, hA3);
    mat3_mul(hA3, hA, hA4);

    double P[3][3], Q[3][3];
    for (int i = 0; i < 3; ++i)
        for (int j = 0; j < 3; ++j) {
            const double I = (i == j) ? 1.0 : 0.0;
            P[i][j] = I + hA[i][j] + hA2[i][j] / 2.0 + hA3[i][j] / 6.0 + hA4[i][j] / 24.0;
            Q[i][j] = h * (I + hA[i][j] / 2.0 + hA2[i][j] / 6.0 + hA3[i][j] / 24.0);
        }

    double P2[3][3], P4[3][3], P8[3][3];
    mat3_mul(P, P, P2);
    mat3_mul(P2, P2, P4);
    mat3_mul(P4, P4, P8);

    // S = I + P + ... + P^7 = (I+P)(I+P^2)(I+P^4)
    double IP[3][3], IP2[3][3], IP4[3][3], T[3][3], S[3][3], R[3][3];
    mat3_copy(P, IP);  mat3_copy(P2, IP2);  mat3_copy(P4, IP4);
    for (int i = 0; i < 3; ++i) { IP[i][i] += 1.0; IP2[i][i] += 1.0; IP4[i][i] += 1.0; }
    mat3_mul(IP, IP2, T);
    mat3_mul(T, IP4, S);
    mat3_mul(S, Q, R);

    Coeffs cf;
    cf.P00 = (float)P8[0][0]; cf.P01 = (float)P8[0][1]; cf.P02 = (float)P8[0][2];
    cf.P10 = (float)P8[1][0]; cf.P11 = (float)P8[1][1]; cf.P12 = (float)P8[1][2];
    cf.P20 = (float)P8[2][0]; cf.P21 = (float)P8[2][1]; cf.P22 = (float)P8[2][2];
    cf.Ku0 = (float)(R[0][2] * c); cf.Ku1 = (float)(R[1][2] * c); cf.Ku2 = (float)(R[2][2] * c);
    cf.G0 = (float)(R[0][1] * 9.81);
    cf.G1 = (float)(R[1][1] * 9.81);
    cf.G2 = (float)(R[2][1] * 9.81);

    const int chunksTotal = (envTotal + CHUNK_ENVS - 1) / CHUNK_ENVS;
    const int wavesNeeded = (chunksTotal + CHUNKS_PER_WAVE - 1) / CHUNKS_PER_WAVE;
    const int blocks = (wavesNeeded + (THREADS / 64) - 1) / (THREADS / 64);
    pointmass_kernel<<<blocks, THREADS, 0, stream>>>(X0, U, Out, envTotal, chunksTotal, cf);
}